// Round 8
// baseline (906.026 us; speedup 1.0000x reference)
//
#include <hip/hip_runtime.h>

#define NN 50000
#define NE 800000
// NN % 8 == 0 -> grid NN/8, 8 nodes/block, NO early returns (post-loop barrier)

typedef _Float16 half2t __attribute__((ext_vector_type(2)));
union H16 { float4 f; half2t p[4]; };   // one 16B LDS read = 8 halves = 4 pairs

__device__ __forceinline__ float silu_f(float x) { return x / (1.0f + __expf(-x)); }

__device__ __forceinline__ float fdot2(half2t a, half2t b, float c) {
#if __has_builtin(__builtin_amdgcn_fdot2)
    return __builtin_amdgcn_fdot2(a, b, c, false);
#else
    return c + (float)a.x * (float)b.x + (float)a.y * (float)b.y;
#endif
}

// ---------------------------------------------------------------------------
// K1: xf[n][o] = float4( (s@W1_s)[o], xv0[o], xv1[o], xv2[o] )
// ---------------------------------------------------------------------------
__global__ __launch_bounds__(256) void k_node_transform(
    const float* __restrict__ node_feats,
    const float* __restrict__ W1_s,
    const float* __restrict__ W1_v,
    float* __restrict__ xf)
{
    __shared__ float sW1s[32 * 32];
    __shared__ float sW1v[32 * 32];
    __shared__ float sfeat[8][128];
    int t = threadIdx.x;
    for (int i = t; i < 1024; i += 256) { sW1s[i] = W1_s[i]; sW1v[i] = W1_v[i]; }
    int nodeBase = blockIdx.x * 8;
    for (int i = t; i < 8 * 128; i += 256) {
        int nn = nodeBase + (i >> 7);
        sfeat[i >> 7][i & 127] = (nn < NN) ? node_feats[(long)nn * 128 + (i & 127)] : 0.0f;
    }
    __syncthreads();
    int g = t >> 5, o = t & 31;
    int n = nodeBase + g;
    if (n >= NN) return;
    float accs = 0.f, acc0 = 0.f, acc1 = 0.f, acc2 = 0.f;
#pragma unroll
    for (int u = 0; u < 32; ++u) {
        float su  = sfeat[g][u];
        float vu0 = sfeat[g][32 + u * 3 + 0];
        float vu1 = sfeat[g][32 + u * 3 + 1];
        float vu2 = sfeat[g][32 + u * 3 + 2];
        float ws = sW1s[u * 32 + o];
        float wv = sW1v[u * 32 + o];
        accs += su * ws;
        acc0 += vu0 * wv;
        acc1 += vu1 * wv;
        acc2 += vu2 * wv;
    }
    float4 r; r.x = accs; r.y = acc0; r.z = acc1; r.w = acc2;
    *(float4*)&xf[((long)n * 32 + o) * 4] = r;
}

// ---------------------------------------------------------------------------
// CSR build: histogram -> single-block scan -> fill
// ---------------------------------------------------------------------------
__global__ __launch_bounds__(256) void k_hist(const int* __restrict__ edge_dst,
                                              int* __restrict__ counts)
{
    int e = blockIdx.x * 256 + threadIdx.x;
    if (e < NE) atomicAdd(&counts[edge_dst[e]], 1);
}

__global__ __launch_bounds__(1024) void k_scan(const int* __restrict__ counts,
                                               int* __restrict__ row_ptr,
                                               int* __restrict__ cursor)
{
    __shared__ int wsum[16];
    __shared__ int carry_s;
    int t = threadIdx.x;
    int lane = t & 63, w = t >> 6;
    if (t == 0) carry_s = 0;
    __syncthreads();
    for (int base = 0; base < NN; base += 1024) {
        int i = base + t;
        int v = (i < NN) ? counts[i] : 0;
        int s = v;
#pragma unroll
        for (int d = 1; d < 64; d <<= 1) {
            int o = __shfl_up(s, d, 64);
            if (lane >= d) s += o;
        }
        if (lane == 63) wsum[w] = s;
        __syncthreads();
        if (w == 0) {
            int ws = (lane < 16) ? wsum[lane] : 0;
#pragma unroll
            for (int d = 1; d < 16; d <<= 1) {
                int o = __shfl_up(ws, d, 64);
                if (lane >= d) ws += o;
            }
            if (lane < 16) wsum[lane] = ws;
        }
        __syncthreads();
        int excl = (s - v) + ((w > 0) ? wsum[w - 1] : 0) + carry_s;
        if (i < NN) { row_ptr[i] = excl; cursor[i] = excl; }
        int total = wsum[15];
        __syncthreads();
        if (t == 0) carry_s += total;
        __syncthreads();
    }
    if (t == 0) row_ptr[NN] = carry_s;
}

__global__ __launch_bounds__(256) void k_fill(const int* __restrict__ edge_dst,
                                              int* __restrict__ cursor,
                                              int* __restrict__ edge_ids)
{
    int e = blockIdx.x * 256 + threadIdx.x;
    if (e < NE) {
        int slot = atomicAdd(&cursor[edge_dst[e]], 1);
        edge_ids[slot] = e;
    }
}

// ---------------------------------------------------------------------------
// k_degsort: counting sort of nodes by degree, DESCENDING (long nodes first).
// Wave-mates (perm neighbors) get near-equal degree -> no exec-mask waste in
// k_gather_t's divergent edge loop; longest blocks launch first (clean tail).
// ---------------------------------------------------------------------------
__global__ __launch_bounds__(1024) void k_degsort(const int* __restrict__ counts,
                                                  int* __restrict__ perm)
{
    __shared__ int bins[256];
    __shared__ int base[256];
    int t = threadIdx.x;
    if (t < 256) bins[t] = 0;
    __syncthreads();
    for (int i = t; i < NN; i += 1024) {
        int d = counts[i]; if (d > 255) d = 255;
        atomicAdd(&bins[d], 1);
    }
    __syncthreads();
    if (t == 0) {
        int run = 0;
        for (int d = 255; d >= 0; --d) { base[d] = run; run += bins[d]; }
    }
    __syncthreads();
    if (t < 256) bins[t] = 0;    // reuse as per-bin cursors
    __syncthreads();
    for (int i = t; i < NN; i += 1024) {
        int d = counts[i]; if (d > 255) d = 255;
        int pos = base[d] + atomicAdd(&bins[d], 1);
        perm[pos] = i;
    }
}

// ---------------------------------------------------------------------------
// k_gather_t: fused per-dst-node kernel (edge MLP + messages + epilogue).
// block = 256 = 8 groups x 32 lanes, group = one node (degree-sorted via
// perm), 8-edge inner blocking, f16 GEMV (v_dot2_f32_f16).
//
// Pipeline: srcv[0..3]/at0/xv0 gathers issued BEFORE the GEMV (~1500 cyc
// hides the dependent eid->src->xf chain); second sub-block's gathers issued
// right after GEMV, hidden under first sub-block's message math.
// VGPR watch: live set ~110-120; MUST stay <=128 (16-wave occupancy quantum,
// m69). WRITE_SIZE must stay 25000 (no spill).
// ---------------------------------------------------------------------------
#define SW2_HBYTES (160 * 72 * 2)          // 23040
#define POOL_BYTES (SW2_HBYTES + 8 * 8 * 128)  // + hh 8KB = 31232

__global__ __launch_bounds__(256, 3) void k_gather_t(
    const float* __restrict__ edge_embedding,
    const float* __restrict__ edge_attrs,
    const int*   __restrict__ edge_src,
    const float* __restrict__ fc_w1,
    const float* __restrict__ fc_b1,
    const float* __restrict__ fc_w2,
    const float* __restrict__ xf,
    const int*   __restrict__ row_ptr,
    const int*   __restrict__ edge_ids,
    const int*   __restrict__ perm,
    const float* __restrict__ node_feats,
    const float* __restrict__ node_attrs,
    const float* __restrict__ W2_s,
    const float* __restrict__ W2_v,
    const float* __restrict__ Wsc_s,
    const float* __restrict__ Wsc_v,
    float* __restrict__ out)
{
    __shared__ __align__(16) unsigned char pool[POOL_BYTES];
    _Float16* swp = (_Float16*)pool;                       // [160][72] halves
    half2t*   hhp = (half2t*)(pool + SW2_HBYTES);          // [8g][8e][32] pairs

    int t = threadIdx.x;
    // stage fc_w2 -> f16 transposed: swp[c*72 + j] = fc_w2[j*160 + c]
    for (int i = t; i < 64 * 160; i += 256) {
        int j = i / 160, c = i - j * 160;
        swp[c * 72 + j] = (_Float16)fc_w2[i];
    }
    __syncthreads();

    int g = t >> 5, lane = t & 31;
    int n = perm[blockIdx.x * 8 + g];    // degree-sorted node

    // first-layer weights for j = 2*lane, 2*lane+1 (register-resident)
    float w1a[8], w1b[8];
#pragma unroll
    for (int q = 0; q < 8; ++q) {
        w1a[q] = fc_w1[q * 64 + 2 * lane];
        w1b[q] = fc_w1[q * 64 + 2 * lane + 1];
    }
    float b1a = fc_b1[2 * lane], b1b = fc_b1[2 * lane + 1];

    int start = row_ptr[n];
    int end   = row_ptr[n + 1];

    float as0 = 0.f, as1 = 0.f;
    float av[9];
#pragma unroll
    for (int p = 0; p < 9; ++p) av[p] = 0.f;

    const float4* xf4 = (const float4*)xf;
    half2t* hme = hhp + g * (8 * 32);    // this group's h block
    const float INV_SQRT3 = 0.5773502691896258f;
    const float INV_SQRT2 = 0.7071067811865476f;
    const float INV_NEI   = 0.25f;

    for (int i0 = start; i0 < end; i0 += 8) {
        int ne = end - i0;               // >= 1
        int eid[8];
#pragma unroll
        for (int k = 0; k < 8; ++k) eid[k] = edge_ids[(k < ne) ? (i0 + k) : i0];

        // ---- prefetch FIRST message sub-block (hidden under GEMV)
        int srcv0[4];
#pragma unroll
        for (int k = 0; k < 4; ++k) srcv0[k] = edge_src[eid[k]];
        float4 at0[4], xv0[4];
#pragma unroll
        for (int k = 0; k < 4; ++k) {
            at0[k] = *(const float4*)&edge_attrs[(long)eid[k] * 4];
            xv0[k] = xf4[(long)srcv0[k] * 32 + lane];
        }

        // ---- hidden layer: h[2l],h[2l+1] per edge, packed half2 -> LDS
#pragma unroll
        for (int k = 0; k < 8; ++k) {
            float4 e0 = *(const float4*)&edge_embedding[(long)eid[k] * 8];
            float4 e1 = *(const float4*)&edge_embedding[(long)eid[k] * 8 + 4];
            float h0 = b1a, h1 = b1b;
            h0 += e0.x * w1a[0] + e0.y * w1a[1] + e0.z * w1a[2] + e0.w * w1a[3];
            h0 += e1.x * w1a[4] + e1.y * w1a[5] + e1.z * w1a[6] + e1.w * w1a[7];
            h1 += e0.x * w1b[0] + e0.y * w1b[1] + e0.z * w1b[2] + e0.w * w1b[3];
            h1 += e1.x * w1b[4] + e1.y * w1b[5] + e1.z * w1b[6] + e1.w * w1b[7];
            half2t hp;
            hp.x = (_Float16)silu_f(h0);
            hp.y = (_Float16)silu_f(h1);
            hme[k * 32 + lane] = hp;
        }
        // same-wave LDS RAW (group-private): in-order DS pipe, no barrier

        // ---- w = h @ fc_w2 (f16 dot2, f32 acc), 8-edge register block
        float acc[5][8];
#pragma unroll
        for (int p = 0; p < 5; ++p)
#pragma unroll
            for (int k = 0; k < 8; ++k) acc[p][k] = 0.f;

#pragma unroll 2
        for (int jq = 0; jq < 8; ++jq) {           // 8 halves (8 j's) per step
            H16 w0, w1, w2, w3, w4;
            w0.f = *(const float4*)&swp[(0 * 32 + lane) * 72 + jq * 8];
            w1.f = *(const float4*)&swp[(1 * 32 + lane) * 72 + jq * 8];
            w2.f = *(const float4*)&swp[(2 * 32 + lane) * 72 + jq * 8];
            w3.f = *(const float4*)&swp[(3 * 32 + lane) * 72 + jq * 8];
            w4.f = *(const float4*)&swp[(4 * 32 + lane) * 72 + jq * 8];
#pragma unroll
            for (int k = 0; k < 8; ++k) {
                H16 hv;
                hv.f = *(const float4*)&hme[k * 32 + jq * 4];   // broadcast
#pragma unroll
                for (int m = 0; m < 4; ++m) {
                    acc[0][k] = fdot2(hv.p[m], w0.p[m], acc[0][k]);
                    acc[1][k] = fdot2(hv.p[m], w1.p[m], acc[1][k]);
                    acc[2][k] = fdot2(hv.p[m], w2.p[m], acc[2][k]);
                    acc[3][k] = fdot2(hv.p[m], w3.p[m], acc[3][k]);
                    acc[4][k] = fdot2(hv.p[m], w4.p[m], acc[4][k]);
                }
            }
        }

        // ---- issue SECOND sub-block gathers (hidden under first messages)
        int srcv1[4];
        float4 at1[4], xv1[4];
        if (ne > 4) {
#pragma unroll
            for (int k = 0; k < 4; ++k) srcv1[k] = edge_src[eid[4 + k]];
#pragma unroll
            for (int k = 0; k < 4; ++k) {
                at1[k] = *(const float4*)&edge_attrs[(long)eid[4 + k] * 4];
                xv1[k] = xf4[(long)srcv1[k] * 32 + lane];
            }
        }

        // ---- messages sub-block 0 (preloaded at0/xv0)
#pragma unroll
        for (int k = 0; k < 4; ++k) {
            if (k >= ne) break;
            float4 a4 = at0[k];
            float xs  = xv0[k].x;
            float xvx = xv0[k].y, xvy = xv0[k].z, xvz = xv0[k].w;
            float w00 = acc[0][k], w01 = acc[1][k], w10 = acc[2][k];
            float w11s = acc[3][k], w11v = acc[4][k];

            as0 += w00 * xs * a4.x;
            float dot = xvx * a4.y + xvy * a4.z + xvz * a4.w;
            as1 += w11s * dot * INV_SQRT3;
            float t01 = w01 * xs;
            av[0] += t01 * a4.y; av[1] += t01 * a4.z; av[2] += t01 * a4.w;
            float t10 = w10 * a4.x;
            av[3] += t10 * xvx; av[4] += t10 * xvy; av[5] += t10 * xvz;
            float k2 = w11v * INV_SQRT2;
            av[6] += k2 * (xvy * a4.w - xvz * a4.z);
            av[7] += k2 * (xvz * a4.y - xvx * a4.w);
            av[8] += k2 * (xvx * a4.z - xvy * a4.y);
        }

        // ---- messages sub-block 1
        if (ne > 4) {
#pragma unroll
            for (int k = 0; k < 4; ++k) {
                int kk = 4 + k;
                if (kk >= ne) break;
                float4 a4 = at1[k];
                float xs  = xv1[k].x;
                float xvx = xv1[k].y, xvy = xv1[k].z, xvz = xv1[k].w;
                float w00 = acc[0][kk], w01 = acc[1][kk], w10 = acc[2][kk];
                float w11s = acc[3][kk], w11v = acc[4][kk];

                as0 += w00 * xs * a4.x;
                float dot = xvx * a4.y + xvy * a4.z + xvz * a4.w;
                as1 += w11s * dot * INV_SQRT3;
                float t01 = w01 * xs;
                av[0] += t01 * a4.y; av[1] += t01 * a4.z; av[2] += t01 * a4.w;
                float t10 = w10 * a4.x;
                av[3] += t10 * xvx; av[4] += t10 * xvy; av[5] += t10 * xvz;
                float k2 = w11v * INV_SQRT2;
                av[6] += k2 * (xvy * a4.w - xvz * a4.z);
                av[7] += k2 * (xvz * a4.y - xvx * a4.w);
                av[8] += k2 * (xvx * a4.z - xvy * a4.y);
            }
        }
    }

    // ---- weights dead; alias pool as epilogue scratch (all threads arrive)
    __syncthreads();
    float* epi = (float*)pool + (g << 9);   // 512 f32/group:
    // [0:64) as | [64:352) av | [352:480) feats | [480:496) attrs

    epi[lane]      = as0 * INV_NEI;
    epi[32 + lane] = as1 * INV_NEI;
#pragma unroll
    for (int p = 0; p < 3; ++p)
#pragma unroll
        for (int c = 0; c < 3; ++c)
            epi[64 + (p * 32 + lane) * 3 + c] = av[p * 3 + c] * INV_NEI;

    *(float4*)&epi[352 + lane * 4] = *(const float4*)&node_feats[(long)n * 128 + lane * 4];
    if (lane < 16) epi[480 + lane] = node_attrs[(long)n * 16 + lane];

    // ---- fused epilogue: W2 GEMVs + Wsc bilinear (t-form) + gate + residual
    int o = lane;
    float ys0 = 0.f, ys1 = 0.f, yv0 = 0.f, yv1 = 0.f, yv2 = 0.f;

#pragma unroll 8
    for (int u = 0; u < 64; ++u) {
        float as = epi[u];
        ys0 += as * W2_s[u * 64 + o];
        ys1 += as * W2_s[u * 64 + 32 + o];
    }
#pragma unroll 8
    for (int u = 0; u < 96; ++u) {
        float wv = W2_v[u * 32 + o];
        yv0 += epi[64 + u * 3 + 0] * wv;
        yv1 += epi[64 + u * 3 + 1] * wv;
        yv2 += epi[64 + u * 3 + 2] * wv;
    }

    float att[16];
#pragma unroll
    for (int a = 0; a < 16; ++a) att[a] = epi[480 + a];

    for (int u = 0; u < 32; ++u) {
        const float* Wsp = &Wsc_s[u * 1024 + o];
        const float* Wvp = &Wsc_v[u * 512 + o];
        float t0 = 0.f, t1 = 0.f, tv = 0.f;
#pragma unroll
        for (int a = 0; a < 16; ++a) {
            float aa = att[a];
            t0 += aa * Wsp[a * 64];
            t1 += aa * Wsp[a * 64 + 32];
            tv += aa * Wvp[a * 32];
        }
        float su = epi[352 + u];
        ys0 += su * t0;
        ys1 += su * t1;
        yv0 += epi[352 + 32 + u * 3 + 0] * tv;
        yv1 += epi[352 + 32 + u * 3 + 1] * tv;
        yv2 += epi[352 + 32 + u * 3 + 2] * tv;
    }

    float os   = silu_f(ys0);
    float gate = silu_f(ys1);
    long base = (long)n * 128;
    out[base + o] = epi[352 + o] + os;
    out[base + 32 + o * 3 + 0] = epi[352 + 32 + o * 3 + 0] + yv0 * gate;
    out[base + 32 + o * 3 + 1] = epi[352 + 32 + o * 3 + 1] + yv1 * gate;
    out[base + 32 + o * 3 + 2] = epi[352 + 32 + o * 3 + 2] + yv2 * gate;
}

// ---------------------------------------------------------------------------
extern "C" void kernel_launch(void* const* d_in, const int* in_sizes, int n_in,
                              void* d_out, int out_size, void* d_ws, size_t ws_size,
                              hipStream_t stream) {
    const float* node_feats     = (const float*)d_in[0];
    const float* node_attrs     = (const float*)d_in[1];
    const float* edge_embedding = (const float*)d_in[2];
    const float* edge_attrs     = (const float*)d_in[3];
    const int*   edge_src       = (const int*)d_in[4];
    const int*   edge_dst       = (const int*)d_in[5];
    const float* W1_s  = (const float*)d_in[6];
    const float* W1_v  = (const float*)d_in[7];
    const float* fc_w1 = (const float*)d_in[8];
    const float* fc_b1 = (const float*)d_in[9];
    const float* fc_w2 = (const float*)d_in[10];
    const float* W2_s  = (const float*)d_in[11];
    const float* W2_v  = (const float*)d_in[12];
    const float* Wsc_s = (const float*)d_in[13];
    const float* Wsc_v = (const float*)d_in[14];
    float* out = (float*)d_out;

    float* ws  = (float*)d_ws;
    float* xf  = ws;                       // NN*32 float4 = NN*128 floats
    int* ibase    = (int*)(ws + (long)NN * 128);
    int* counts   = ibase;                 // NN
    int* row_ptr  = ibase + NN;            // NN+1
    int* cursor   = ibase + 2 * NN + 1;    // NN
    int* edge_ids = ibase + 3 * NN + 1;    // NE
    int* perm     = ibase + 3 * NN + 1 + NE; // NN

    hipMemsetAsync(counts, 0, (size_t)NN * sizeof(int), stream);
    k_hist<<<(NE + 255) / 256, 256, 0, stream>>>(edge_dst, counts);
    k_node_transform<<<(NN + 7) / 8, 256, 0, stream>>>(node_feats, W1_s, W1_v, xf);
    k_degsort<<<1, 1024, 0, stream>>>(counts, perm);
    k_scan<<<1, 1024, 0, stream>>>(counts, row_ptr, cursor);
    k_fill<<<(NE + 255) / 256, 256, 0, stream>>>(edge_dst, cursor, edge_ids);
    k_gather_t<<<NN / 8, 256, 0, stream>>>(edge_embedding, edge_attrs, edge_src,
                                           fc_w1, fc_b1, fc_w2, xf,
                                           row_ptr, edge_ids, perm,
                                           node_feats, node_attrs,
                                           W2_s, W2_v, Wsc_s, Wsc_v, out);
}

// Round 9
// 793.448 us; speedup vs baseline: 1.1419x; 1.1419x over previous
//
#include <hip/hip_runtime.h>

#define NN 50000
#define NE 800000
// NN % 8 == 0 -> grid NN/8, 8 nodes/block, NO early returns (post-loop barrier)

typedef _Float16 half2t __attribute__((ext_vector_type(2)));
union H16 { float4 f; half2t p[4]; };   // one 16B LDS read = 8 halves = 4 pairs

__device__ __forceinline__ float silu_f(float x) { return x / (1.0f + __expf(-x)); }

__device__ __forceinline__ float fdot2(half2t a, half2t b, float c) {
#if __has_builtin(__builtin_amdgcn_fdot2)
    return __builtin_amdgcn_fdot2(a, b, c, false);
#else
    return c + (float)a.x * (float)b.x + (float)a.y * (float)b.y;
#endif
}

// ---------------------------------------------------------------------------
// K1: xf[n][o] = float4( (s@W1_s)[o], xv0[o], xv1[o], xv2[o] )
// ---------------------------------------------------------------------------
__global__ __launch_bounds__(256) void k_node_transform(
    const float* __restrict__ node_feats,
    const float* __restrict__ W1_s,
    const float* __restrict__ W1_v,
    float* __restrict__ xf)
{
    __shared__ float sW1s[32 * 32];
    __shared__ float sW1v[32 * 32];
    __shared__ float sfeat[8][128];
    int t = threadIdx.x;
    for (int i = t; i < 1024; i += 256) { sW1s[i] = W1_s[i]; sW1v[i] = W1_v[i]; }
    int nodeBase = blockIdx.x * 8;
    for (int i = t; i < 8 * 128; i += 256) {
        int nn = nodeBase + (i >> 7);
        sfeat[i >> 7][i & 127] = (nn < NN) ? node_feats[(long)nn * 128 + (i & 127)] : 0.0f;
    }
    __syncthreads();
    int g = t >> 5, o = t & 31;
    int n = nodeBase + g;
    if (n >= NN) return;
    float accs = 0.f, acc0 = 0.f, acc1 = 0.f, acc2 = 0.f;
#pragma unroll
    for (int u = 0; u < 32; ++u) {
        float su  = sfeat[g][u];
        float vu0 = sfeat[g][32 + u * 3 + 0];
        float vu1 = sfeat[g][32 + u * 3 + 1];
        float vu2 = sfeat[g][32 + u * 3 + 2];
        float ws = sW1s[u * 32 + o];
        float wv = sW1v[u * 32 + o];
        accs += su * ws;
        acc0 += vu0 * wv;
        acc1 += vu1 * wv;
        acc2 += vu2 * wv;
    }
    float4 r; r.x = accs; r.y = acc0; r.z = acc1; r.w = acc2;
    *(float4*)&xf[((long)n * 32 + o) * 4] = r;
}

// ---------------------------------------------------------------------------
// CSR build: histogram -> single-block scan -> fill
// ---------------------------------------------------------------------------
__global__ __launch_bounds__(256) void k_hist(const int* __restrict__ edge_dst,
                                              int* __restrict__ counts)
{
    int e = blockIdx.x * 256 + threadIdx.x;
    if (e < NE) atomicAdd(&counts[edge_dst[e]], 1);
}

__global__ __launch_bounds__(1024) void k_scan(const int* __restrict__ counts,
                                               int* __restrict__ row_ptr,
                                               int* __restrict__ cursor)
{
    __shared__ int wsum[16];
    __shared__ int carry_s;
    int t = threadIdx.x;
    int lane = t & 63, w = t >> 6;
    if (t == 0) carry_s = 0;
    __syncthreads();
    for (int base = 0; base < NN; base += 1024) {
        int i = base + t;
        int v = (i < NN) ? counts[i] : 0;
        int s = v;
#pragma unroll
        for (int d = 1; d < 64; d <<= 1) {
            int o = __shfl_up(s, d, 64);
            if (lane >= d) s += o;
        }
        if (lane == 63) wsum[w] = s;
        __syncthreads();
        if (w == 0) {
            int ws = (lane < 16) ? wsum[lane] : 0;
#pragma unroll
            for (int d = 1; d < 16; d <<= 1) {
                int o = __shfl_up(ws, d, 64);
                if (lane >= d) ws += o;
            }
            if (lane < 16) wsum[lane] = ws;
        }
        __syncthreads();
        int excl = (s - v) + ((w > 0) ? wsum[w - 1] : 0) + carry_s;
        if (i < NN) { row_ptr[i] = excl; cursor[i] = excl; }
        int total = wsum[15];
        __syncthreads();
        if (t == 0) carry_s += total;
        __syncthreads();
    }
    if (t == 0) row_ptr[NN] = carry_s;
}

__global__ __launch_bounds__(256) void k_fill(const int* __restrict__ edge_dst,
                                              int* __restrict__ cursor,
                                              int* __restrict__ edge_ids)
{
    int e = blockIdx.x * 256 + threadIdx.x;
    if (e < NE) {
        int slot = atomicAdd(&cursor[edge_dst[e]], 1);
        edge_ids[slot] = e;
    }
}

// ---------------------------------------------------------------------------
// k_degsort: counting sort of nodes by degree, DESCENDING (long nodes first).
// Wave-mates (perm neighbors) get near-equal degree -> no exec-mask waste in
// k_gather_t's divergent edge loop; longest blocks launch first (clean tail).
// ---------------------------------------------------------------------------
__global__ __launch_bounds__(1024) void k_degsort(const int* __restrict__ counts,
                                                  int* __restrict__ perm)
{
    __shared__ int bins[256];
    __shared__ int base[256];
    int t = threadIdx.x;
    if (t < 256) bins[t] = 0;
    __syncthreads();
    for (int i = t; i < NN; i += 1024) {
        int d = counts[i]; if (d > 255) d = 255;
        atomicAdd(&bins[d], 1);
    }
    __syncthreads();
    if (t == 0) {
        int run = 0;
        for (int d = 255; d >= 0; --d) { base[d] = run; run += bins[d]; }
    }
    __syncthreads();
    if (t < 256) bins[t] = 0;    // reuse as per-bin cursors
    __syncthreads();
    for (int i = t; i < NN; i += 1024) {
        int d = counts[i]; if (d > 255) d = 255;
        int pos = base[d] + atomicAdd(&bins[d], 1);
        perm[pos] = i;
    }
}

// ---------------------------------------------------------------------------
// k_gather_t: fused per-dst-node kernel (edge MLP + messages + epilogue).
// EXACT R6 structure (best measured: 607us @ 41.7% occ) + perm indirection.
// block = 256 = 8 groups x 32 lanes, group = one node (degree-sorted),
// 8-edge inner blocking, f16 GEMV via v_dot2_f32_f16.
//
// (256,4): allocator targets 64 VGPR -> ~115MB spill traffic, but 5 blocks/CU
// (20 waves) beats the spill-free 76-VGPR 4-block build by 36us (R6 vs R7).
// Occupancy quantum (m69): waves halve at VGPR 64/128 -> 64-with-spill is the
// local optimum. Spill-profile check: WRITE_SIZE ~= 93750 KB.
// ---------------------------------------------------------------------------
#define SW2_HBYTES (160 * 72 * 2)          // 23040
#define POOL_BYTES (SW2_HBYTES + 8 * 8 * 128)  // + hh 8KB = 31232

__global__ __launch_bounds__(256, 4) void k_gather_t(
    const float* __restrict__ edge_embedding,
    const float* __restrict__ edge_attrs,
    const int*   __restrict__ edge_src,
    const float* __restrict__ fc_w1,
    const float* __restrict__ fc_b1,
    const float* __restrict__ fc_w2,
    const float* __restrict__ xf,
    const int*   __restrict__ row_ptr,
    const int*   __restrict__ edge_ids,
    const int*   __restrict__ perm,
    const float* __restrict__ node_feats,
    const float* __restrict__ node_attrs,
    const float* __restrict__ W2_s,
    const float* __restrict__ W2_v,
    const float* __restrict__ Wsc_s,
    const float* __restrict__ Wsc_v,
    float* __restrict__ out)
{
    __shared__ __align__(16) unsigned char pool[POOL_BYTES];
    _Float16* swp = (_Float16*)pool;                       // [160][72] halves
    half2t*   hhp = (half2t*)(pool + SW2_HBYTES);          // [8g][8e][32] pairs

    int t = threadIdx.x;
    // stage fc_w2 -> f16 transposed: swp[c*72 + j] = fc_w2[j*160 + c]
    for (int i = t; i < 64 * 160; i += 256) {
        int j = i / 160, c = i - j * 160;
        swp[c * 72 + j] = (_Float16)fc_w2[i];
    }
    __syncthreads();

    int g = t >> 5, lane = t & 31;
    int n = perm[blockIdx.x * 8 + g];    // degree-sorted node

    // first-layer weights for j = 2*lane, 2*lane+1 (register-resident)
    float w1a[8], w1b[8];
#pragma unroll
    for (int q = 0; q < 8; ++q) {
        w1a[q] = fc_w1[q * 64 + 2 * lane];
        w1b[q] = fc_w1[q * 64 + 2 * lane + 1];
    }
    float b1a = fc_b1[2 * lane], b1b = fc_b1[2 * lane + 1];

    int start = row_ptr[n];
    int end   = row_ptr[n + 1];

    float as0 = 0.f, as1 = 0.f;
    float av[9];
#pragma unroll
    for (int p = 0; p < 9; ++p) av[p] = 0.f;

    const float4* xf4 = (const float4*)xf;
    half2t* hme = hhp + g * (8 * 32);    // this group's h block
    const float INV_SQRT3 = 0.5773502691896258f;
    const float INV_SQRT2 = 0.7071067811865476f;
    const float INV_NEI   = 0.25f;

    for (int i0 = start; i0 < end; i0 += 8) {
        int ne = end - i0;               // >= 1
        int eid[8];
#pragma unroll
        for (int k = 0; k < 8; ++k) eid[k] = edge_ids[(k < ne) ? (i0 + k) : i0];

        // ---- hidden layer: h[2l],h[2l+1] per edge, packed half2 -> LDS
#pragma unroll
        for (int k = 0; k < 8; ++k) {
            float4 e0 = *(const float4*)&edge_embedding[(long)eid[k] * 8];
            float4 e1 = *(const float4*)&edge_embedding[(long)eid[k] * 8 + 4];
            float h0 = b1a, h1 = b1b;
            h0 += e0.x * w1a[0] + e0.y * w1a[1] + e0.z * w1a[2] + e0.w * w1a[3];
            h0 += e1.x * w1a[4] + e1.y * w1a[5] + e1.z * w1a[6] + e1.w * w1a[7];
            h1 += e0.x * w1b[0] + e0.y * w1b[1] + e0.z * w1b[2] + e0.w * w1b[3];
            h1 += e1.x * w1b[4] + e1.y * w1b[5] + e1.z * w1b[6] + e1.w * w1b[7];
            half2t hp;
            hp.x = (_Float16)silu_f(h0);
            hp.y = (_Float16)silu_f(h1);
            hme[k * 32 + lane] = hp;
        }
        // same-wave LDS RAW (group-private): in-order DS pipe, no barrier

        // ---- w = h @ fc_w2 (f16 dot2, f32 acc), 8-edge register block
        float acc[5][8];
#pragma unroll
        for (int p = 0; p < 5; ++p)
#pragma unroll
            for (int k = 0; k < 8; ++k) acc[p][k] = 0.f;

#pragma unroll 2
        for (int jq = 0; jq < 8; ++jq) {           // 8 halves (8 j's) per step
            H16 w0, w1, w2, w3, w4;
            w0.f = *(const float4*)&swp[(0 * 32 + lane) * 72 + jq * 8];
            w1.f = *(const float4*)&swp[(1 * 32 + lane) * 72 + jq * 8];
            w2.f = *(const float4*)&swp[(2 * 32 + lane) * 72 + jq * 8];
            w3.f = *(const float4*)&swp[(3 * 32 + lane) * 72 + jq * 8];
            w4.f = *(const float4*)&swp[(4 * 32 + lane) * 72 + jq * 8];
#pragma unroll
            for (int k = 0; k < 8; ++k) {
                H16 hv;
                hv.f = *(const float4*)&hme[k * 32 + jq * 4];   // broadcast
#pragma unroll
                for (int m = 0; m < 4; ++m) {
                    acc[0][k] = fdot2(hv.p[m], w0.p[m], acc[0][k]);
                    acc[1][k] = fdot2(hv.p[m], w1.p[m], acc[1][k]);
                    acc[2][k] = fdot2(hv.p[m], w2.p[m], acc[2][k]);
                    acc[3][k] = fdot2(hv.p[m], w3.p[m], acc[3][k]);
                    acc[4][k] = fdot2(hv.p[m], w4.p[m], acc[4][k]);
                }
            }
        }

        // ---- messages, 2 sub-blocks of 4 (bounded preload register cost)
#pragma unroll
        for (int h0i = 0; h0i < 8; h0i += 4) {
            if (h0i >= ne) break;
            int srcv[4];
#pragma unroll
            for (int k = 0; k < 4; ++k) srcv[k] = edge_src[eid[h0i + k]];
            float4 at[4], xv[4];
#pragma unroll
            for (int k = 0; k < 4; ++k) {
                at[k] = *(const float4*)&edge_attrs[(long)eid[h0i + k] * 4];
                xv[k] = xf4[(long)srcv[k] * 32 + lane];
            }
#pragma unroll
            for (int k = 0; k < 4; ++k) {
                int kk = h0i + k;
                if (kk >= ne) break;
                float4 a4 = at[k];
                float xs  = xv[k].x;
                float xv0 = xv[k].y, xv1 = xv[k].z, xv2 = xv[k].w;
                float w00 = acc[0][kk], w01 = acc[1][kk], w10 = acc[2][kk];
                float w11s = acc[3][kk], w11v = acc[4][kk];

                as0 += w00 * xs * a4.x;
                float dot = xv0 * a4.y + xv1 * a4.z + xv2 * a4.w;
                as1 += w11s * dot * INV_SQRT3;
                float t01 = w01 * xs;
                av[0] += t01 * a4.y; av[1] += t01 * a4.z; av[2] += t01 * a4.w;
                float t10 = w10 * a4.x;
                av[3] += t10 * xv0; av[4] += t10 * xv1; av[5] += t10 * xv2;
                float k2 = w11v * INV_SQRT2;
                av[6] += k2 * (xv1 * a4.w - xv2 * a4.z);
                av[7] += k2 * (xv2 * a4.y - xv0 * a4.w);
                av[8] += k2 * (xv0 * a4.z - xv1 * a4.y);
            }
        }
    }

    // ---- weights dead; alias pool as epilogue scratch (all threads arrive)
    __syncthreads();
    float* epi = (float*)pool + (g << 9);   // 512 f32/group:
    // [0:64) as | [64:352) av | [352:480) feats | [480:496) attrs

    epi[lane]      = as0 * INV_NEI;
    epi[32 + lane] = as1 * INV_NEI;
#pragma unroll
    for (int p = 0; p < 3; ++p)
#pragma unroll
        for (int c = 0; c < 3; ++c)
            epi[64 + (p * 32 + lane) * 3 + c] = av[p * 3 + c] * INV_NEI;

    *(float4*)&epi[352 + lane * 4] = *(const float4*)&node_feats[(long)n * 128 + lane * 4];
    if (lane < 16) epi[480 + lane] = node_attrs[(long)n * 16 + lane];

    // ---- fused epilogue: W2 GEMVs + Wsc bilinear (t-form) + gate + residual
    int o = lane;
    float ys0 = 0.f, ys1 = 0.f, yv0 = 0.f, yv1 = 0.f, yv2 = 0.f;

#pragma unroll 8
    for (int u = 0; u < 64; ++u) {
        float as = epi[u];
        ys0 += as * W2_s[u * 64 + o];
        ys1 += as * W2_s[u * 64 + 32 + o];
    }
#pragma unroll 8
    for (int u = 0; u < 96; ++u) {
        float wv = W2_v[u * 32 + o];
        yv0 += epi[64 + u * 3 + 0] * wv;
        yv1 += epi[64 + u * 3 + 1] * wv;
        yv2 += epi[64 + u * 3 + 2] * wv;
    }

    float att[16];
#pragma unroll
    for (int a = 0; a < 16; ++a) att[a] = epi[480 + a];

    for (int u = 0; u < 32; ++u) {
        const float* Wsp = &Wsc_s[u * 1024 + o];
        const float* Wvp = &Wsc_v[u * 512 + o];
        float t0 = 0.f, t1 = 0.f, tv = 0.f;
#pragma unroll
        for (int a = 0; a < 16; ++a) {
            float aa = att[a];
            t0 += aa * Wsp[a * 64];
            t1 += aa * Wsp[a * 64 + 32];
            tv += aa * Wvp[a * 32];
        }
        float su = epi[352 + u];
        ys0 += su * t0;
        ys1 += su * t1;
        yv0 += epi[352 + 32 + u * 3 + 0] * tv;
        yv1 += epi[352 + 32 + u * 3 + 1] * tv;
        yv2 += epi[352 + 32 + u * 3 + 2] * tv;
    }

    float os   = silu_f(ys0);
    float gate = silu_f(ys1);
    long base = (long)n * 128;
    out[base + o] = epi[352 + o] + os;
    out[base + 32 + o * 3 + 0] = epi[352 + 32 + o * 3 + 0] + yv0 * gate;
    out[base + 32 + o * 3 + 1] = epi[352 + 32 + o * 3 + 1] + yv1 * gate;
    out[base + 32 + o * 3 + 2] = epi[352 + 32 + o * 3 + 2] + yv2 * gate;
}

// ---------------------------------------------------------------------------
extern "C" void kernel_launch(void* const* d_in, const int* in_sizes, int n_in,
                              void* d_out, int out_size, void* d_ws, size_t ws_size,
                              hipStream_t stream) {
    const float* node_feats     = (const float*)d_in[0];
    const float* node_attrs     = (const float*)d_in[1];
    const float* edge_embedding = (const float*)d_in[2];
    const float* edge_attrs     = (const float*)d_in[3];
    const int*   edge_src       = (const int*)d_in[4];
    const int*   edge_dst       = (const int*)d_in[5];
    const float* W1_s  = (const float*)d_in[6];
    const float* W1_v  = (const float*)d_in[7];
    const float* fc_w1 = (const float*)d_in[8];
    const float* fc_b1 = (const float*)d_in[9];
    const float* fc_w2 = (const float*)d_in[10];
    const float* W2_s  = (const float*)d_in[11];
    const float* W2_v  = (const float*)d_in[12];
    const float* Wsc_s = (const float*)d_in[13];
    const float* Wsc_v = (const float*)d_in[14];
    float* out = (float*)d_out;

    float* ws  = (float*)d_ws;
    float* xf  = ws;                       // NN*32 float4 = NN*128 floats
    int* ibase    = (int*)(ws + (long)NN * 128);
    int* counts   = ibase;                 // NN
    int* row_ptr  = ibase + NN;            // NN+1
    int* cursor   = ibase + 2 * NN + 1;    // NN
    int* edge_ids = ibase + 3 * NN + 1;    // NE
    int* perm     = ibase + 3 * NN + 1 + NE; // NN

    hipMemsetAsync(counts, 0, (size_t)NN * sizeof(int), stream);
    k_hist<<<(NE + 255) / 256, 256, 0, stream>>>(edge_dst, counts);
    k_node_transform<<<(NN + 7) / 8, 256, 0, stream>>>(node_feats, W1_s, W1_v, xf);
    k_degsort<<<1, 1024, 0, stream>>>(counts, perm);
    k_scan<<<1, 1024, 0, stream>>>(counts, row_ptr, cursor);
    k_fill<<<(NE + 255) / 256, 256, 0, stream>>>(edge_dst, cursor, edge_ids);
    k_gather_t<<<NN / 8, 256, 0, stream>>>(edge_embedding, edge_attrs, edge_src,
                                           fc_w1, fc_b1, fc_w2, xf,
                                           row_ptr, edge_ids, perm,
                                           node_feats, node_attrs,
                                           W2_s, W2_v, Wsc_s, Wsc_v, out);
}